// Round 1
// baseline (338.964 us; speedup 1.0000x reference)
//
#include <hip/hip_runtime.h>
#include <math.h>

// LSEP loss: log1p( sum_i sum_{j!=y_i} exp(x[i,j] - x[i,y_i]) )
//   = log1p( sum_i exp(-pos_i) * sum_j exp(x[i,j])  -  B )
// C = 340, divisible by 4 -> every float4 lies within one row, row = idx4/85.
// n4 = 65536*85 = 5,570,560 = 8 * 696,320 -> each thread does exactly 8
// float4s (UNROLL=8), grid = 2720 blocks x 256 threads, zero tail.
//
// R1 lesson: flat grid-stride loop compiled to 8 VGPRs / zero ILP ->
// latency-bound. Batched loads (2 memory epochs) fixed that.
// R2 lesson (this version): the timed window is dominated by two ~55us
// harness re-poison fills (356 MB @ 6.5 TB/s); lsep_main itself is ~15us,
// within ~10% of its 14.2us HBM roofline (89.1 MB compulsory read).
// The only controllable structural cost left is the second dispatch
// (lsep_reduce exec + in-graph gap ~4-5us). This version folds the final
// reduce into the main kernel via the last-block-done pattern:
//  - per-block partials stored with AGENT scope (per-XCD L2s are NOT
//    coherent; plain stores could sit dirty in the writer XCD's L2 and
//    intra-kernel there is no dispatch-boundary flush to save us)
//  - __device__ g_count is module-load-zeroed (no init dispatch needed)
//    and self-reset by the last block, so graph replays stay correct
//  - deliberately NOT same-address double atomicAdd: 2720 fp64 RMWs to
//    one cacheline arrive completion-clustered and would serialize.

#define NCLS 340
#define NCLS4 85
#define UNROLL 8

__device__ unsigned g_count = 0u;   // zeroed at module load; self-resetting

__global__ void __launch_bounds__(256) lsep_fused(
        const float* __restrict__ in,
        const int* __restrict__ tgt,
        double* __restrict__ partial,
        float* __restrict__ out,
        int B, int nblocks) {
    const int tid = blockIdx.x * blockDim.x + threadIdx.x;
    const int T = gridDim.x * blockDim.x;     // total threads = n4/8
    const float4* __restrict__ in4 = (const float4*)in;

    int   idx[UNROLL], row[UNROLL], t[UNROLL];
    float4 v[UNROLL];
    float pos[UNROLL];

    // epoch 1: issue all v-loads and tgt-loads (independent)
    #pragma unroll
    for (int u = 0; u < UNROLL; ++u) {
        idx[u] = tid + u * T;
        row[u] = idx[u] / NCLS4;              // magic-mul
        v[u]   = in4[idx[u]];
    }
    #pragma unroll
    for (int u = 0; u < UNROLL; ++u)
        t[u] = tgt[row[u]];

    // epoch 2: dependent pos gathers (L1/L2-warm: 85 consecutive tids share
    // a row, so these are near-broadcast)
    #pragma unroll
    for (int u = 0; u < UNROLL; ++u)
        pos[u] = in[row[u] * NCLS + t[u]];

    float s = 0.0f;
    #pragma unroll
    for (int u = 0; u < UNROLL; ++u) {
        float e = __expf(v[u].x) + __expf(v[u].y) +
                  __expf(v[u].z) + __expf(v[u].w);
        s += e * __expf(-pos[u]);
    }

    // wave reduce (64 lanes)
    #pragma unroll
    for (int off = 32; off > 0; off >>= 1)
        s += __shfl_down(s, off, 64);

    __shared__ float wsum[4];
    __shared__ int   isLast;
    const int lane = threadIdx.x & 63;
    const int wave = threadIdx.x >> 6;
    if (lane == 0) wsum[wave] = s;
    __syncthreads();

    if (threadIdx.x == 0) {
        double bs = (double)(wsum[0] + wsum[1] + wsum[2] + wsum[3]);
        // agent-scope release store: visible past this XCD's L2
        __hip_atomic_store(&partial[blockIdx.x], bs,
                           __ATOMIC_RELEASE, __HIP_MEMORY_SCOPE_AGENT);
        unsigned prev = __hip_atomic_fetch_add(&g_count, 1u,
                           __ATOMIC_ACQ_REL, __HIP_MEMORY_SCOPE_AGENT);
        isLast = (prev == (unsigned)nblocks - 1u) ? 1 : 0;
    }
    __syncthreads();
    if (isLast == 0) return;

    // last block: all 2720 partials are published (acq_rel RMW chain on
    // g_count synchronizes with each block's release store). Agent-scope
    // loads bypass potentially-stale caches.
    double d = 0.0;
    for (int i = threadIdx.x; i < nblocks; i += 256)
        d += __hip_atomic_load(&partial[i], __ATOMIC_RELAXED,
                               __HIP_MEMORY_SCOPE_AGENT);
    #pragma unroll
    for (int off = 32; off > 0; off >>= 1)
        d += __shfl_down(d, off, 64);

    __shared__ double dsum[4];
    if (lane == 0) dsum[wave] = d;
    __syncthreads();
    if (threadIdx.x == 0) {
        double total = dsum[0] + dsum[1] + dsum[2] + dsum[3];
        out[0] = (float)log1p(total - (double)B);  // remove j==y_i terms
        // reset for the next graph replay (stream-ordered, so no race)
        __hip_atomic_store(&g_count, 0u,
                           __ATOMIC_RELAXED, __HIP_MEMORY_SCOPE_AGENT);
    }
}

extern "C" void kernel_launch(void* const* d_in, const int* in_sizes, int n_in,
                              void* d_out, int out_size, void* d_ws, size_t ws_size,
                              hipStream_t stream) {
    const float* in  = (const float*)d_in[0];
    const int*   tgt = (const int*)d_in[1];
    const int B  = in_sizes[1];          // 65536 rows
    const int n4 = in_sizes[0] / 4;      // 5,570,560 float4s

    const int threads = n4 / UNROLL;     // 696,320 (exact)
    const int blocks  = threads / 256;   // 2720 (exact)

    double* partial = (double*)d_ws;     // 2720 * 8B = 21.8 KB scratch

    lsep_fused<<<blocks, 256, 0, stream>>>(in, tgt, partial,
                                           (float*)d_out, B, blocks);
}

// Round 3
// 243.158 us; speedup vs baseline: 1.3940x; 1.3940x over previous
//
#include <hip/hip_runtime.h>
#include <math.h>

// LSEP loss: log1p( sum_i sum_{j!=y_i} exp(x[i,j] - x[i,y_i]) )
//   = log1p( sum_i exp(-pos_i) * sum_j exp(x[i,j])  -  B )
// C = 340, divisible by 4 -> every float4 lies within one row, row = idx4/85.
// n4 = 65536*85 = 5,570,560 = 8 * 696,320 -> each thread does exactly 8
// float4s (UNROLL=8), grid = 2720 blocks x 256 threads, zero tail.
//
// R1 lesson: flat grid-stride loop -> zero ILP -> latency-bound. Batched
//   loads (2 memory epochs) fixed that; main body ~15us, near its 14.2us
//   compulsory-read roofline.
// R2 lesson: fusing the final reduce with an ACQ_REL agent-scope RMW per
//   block was a 16x regression (243us, VALUBusy 2%, one replay showed
//   FETCH~0 yet still 243us). Mechanism: agent-scope ACQUIRE on gfx950
//   emits buffer_inv sc1 = full per-XCD L2 invalidate. 2720 blocks each
//   wiped their XCD's L2 -> caches permanently cold for all resident
//   waves -> every load at coherent-point latency, no ILP to hide it.
// R3: only the WINNER needs acquire. Losers publish with a RELAXED agent
//   store (write-through, no maintenance) + RELEASE RMW on the counter
//   (s_waitcnt + clean-L2 writeback, NO invalidate). The single buffer_inv
//   lives in the last block only. (R3 failed to compile: __hip_atomic_fence
//   is not in this ROCm's headers; R4 uses __builtin_amdgcn_fence.)

#define NCLS 340
#define NCLS4 85
#define UNROLL 8

__device__ unsigned g_count = 0u;   // zeroed at module load; self-resetting

__global__ void __launch_bounds__(256) lsep_fused(
        const float* __restrict__ in,
        const int* __restrict__ tgt,
        double* __restrict__ partial,
        float* __restrict__ out,
        int B, int nblocks) {
    const int tid = blockIdx.x * blockDim.x + threadIdx.x;
    const int T = gridDim.x * blockDim.x;     // total threads = n4/8
    const float4* __restrict__ in4 = (const float4*)in;

    int   idx[UNROLL], row[UNROLL], t[UNROLL];
    float4 v[UNROLL];
    float pos[UNROLL];

    // epoch 1: issue all v-loads and tgt-loads (independent)
    #pragma unroll
    for (int u = 0; u < UNROLL; ++u) {
        idx[u] = tid + u * T;
        row[u] = idx[u] / NCLS4;              // magic-mul
        v[u]   = in4[idx[u]];
    }
    #pragma unroll
    for (int u = 0; u < UNROLL; ++u)
        t[u] = tgt[row[u]];

    // epoch 2: dependent pos gathers (L1/L2-warm: 85 consecutive tids share
    // a row, so these are near-broadcast)
    #pragma unroll
    for (int u = 0; u < UNROLL; ++u)
        pos[u] = in[row[u] * NCLS + t[u]];

    float s = 0.0f;
    #pragma unroll
    for (int u = 0; u < UNROLL; ++u) {
        float e = __expf(v[u].x) + __expf(v[u].y) +
                  __expf(v[u].z) + __expf(v[u].w);
        s += e * __expf(-pos[u]);
    }

    // wave reduce (64 lanes)
    #pragma unroll
    for (int off = 32; off > 0; off >>= 1)
        s += __shfl_down(s, off, 64);

    __shared__ float wsum[4];
    __shared__ int   isLast;
    const int lane = threadIdx.x & 63;
    const int wave = threadIdx.x >> 6;
    if (lane == 0) wsum[wave] = s;
    __syncthreads();

    if (threadIdx.x == 0) {
        double bs = (double)(wsum[0] + wsum[1] + wsum[2] + wsum[3]);
        // RELAXED agent store: write-through past this XCD's L2, no cache
        // maintenance. Visibility ordering comes from the RELEASE RMW below.
        __hip_atomic_store(&partial[blockIdx.x], bs,
                           __ATOMIC_RELAXED, __HIP_MEMORY_SCOPE_AGENT);
        // RELEASE RMW: s_waitcnt vmcnt(0) + clean-L2 writeback before the
        // atomic — NO buffer_inv. Orders the partial store before the count.
        unsigned prev = __hip_atomic_fetch_add(&g_count, 1u,
                           __ATOMIC_RELEASE, __HIP_MEMORY_SCOPE_AGENT);
        isLast = (prev == (unsigned)nblocks - 1u) ? 1 : 0;
        if (isLast) {
            // the ONLY acquire (buffer_inv sc1) in the whole kernel —
            // executed once, by one thread, after all 2720 release-RMWs.
            __builtin_amdgcn_fence(__ATOMIC_ACQUIRE, "agent");
        }
    }
    __syncthreads();
    if (isLast == 0) return;

    // last block: reduce the 2720 partials with relaxed agent loads
    // (read from the coherent point; stale L2 lines were just invalidated).
    double d = 0.0;
    for (int i = threadIdx.x; i < nblocks; i += 256)
        d += __hip_atomic_load(&partial[i], __ATOMIC_RELAXED,
                               __HIP_MEMORY_SCOPE_AGENT);
    #pragma unroll
    for (int off = 32; off > 0; off >>= 1)
        d += __shfl_down(d, off, 64);

    __shared__ double dsum[4];
    if (lane == 0) dsum[wave] = d;
    __syncthreads();
    if (threadIdx.x == 0) {
        double total = dsum[0] + dsum[1] + dsum[2] + dsum[3];
        out[0] = (float)log1p(total - (double)B);  // remove j==y_i terms
        // reset for the next graph replay (stream-ordered, so no race)
        __hip_atomic_store(&g_count, 0u,
                           __ATOMIC_RELAXED, __HIP_MEMORY_SCOPE_AGENT);
    }
}

extern "C" void kernel_launch(void* const* d_in, const int* in_sizes, int n_in,
                              void* d_out, int out_size, void* d_ws, size_t ws_size,
                              hipStream_t stream) {
    const float* in  = (const float*)d_in[0];
    const int*   tgt = (const int*)d_in[1];
    const int B  = in_sizes[1];          // 65536 rows
    const int n4 = in_sizes[0] / 4;      // 5,570,560 float4s

    const int threads = n4 / UNROLL;     // 696,320 (exact)
    const int blocks  = threads / 256;   // 2720 (exact)

    double* partial = (double*)d_ws;     // 2720 * 8B = 21.8 KB scratch

    lsep_fused<<<blocks, 256, 0, stream>>>(in, tgt, partial,
                                           (float*)d_out, B, blocks);
}

// Round 4
// 144.400 us; speedup vs baseline: 2.3474x; 1.6839x over previous
//
#include <hip/hip_runtime.h>
#include <math.h>

// LSEP loss: log1p( sum_i sum_{j!=y_i} exp(x[i,j] - x[i,y_i]) )
//   = log1p( sum_i exp(-pos_i) * sum_j exp(x[i,j])  -  B )
// C = 340, divisible by 4 -> every float4 lies within one row, row = idx4/85.
// n4 = 65536*85 = 5,570,560 = 8 * 696,320 -> each thread does exactly 8
// float4s (UNROLL=8), grid = 2720 blocks x 256 threads, zero tail.
//
// R1 lesson: flat grid-stride loop -> zero ILP -> latency-bound. Batched
//   loads (2 memory epochs) fixed that; main body ~15us.
// R2 lesson: per-block ACQ_REL agent RMW = 243us. Agent ACQUIRE emits
//   buffer_inv sc1 (full per-XCD L2 invalidate) -> caches permanently cold.
// R4 lesson: winner-only acquire = 144us, STILL traffic-independent
//   (replays: FETCH~0.17MB, same 144us). Remaining culprit: per-block
//   agent RELEASE emits buffer_wbl2 sc1 — an L2 writeback WALK, 2720 of
//   them (~340/XCD), each stalling that XCD's L2 pipe.
// R5 (this version): wbl2 only exists to flush PLAIN stores — but this
//   kernel has none (the partial publish is already an sc1 atomic store
//   that writes through to the coherent point). So:
//     losers:  sc1 relaxed store -> bare s_waitcnt vmcnt(0) (waits for
//              the coherent-point ack = the only ordering we need) ->
//              RELAXED u32 RMW on g_count. No wbl2.
//     winner:  relaxed agent (sc1) atomic loads read the coherent point
//              directly — stale L2 bypassed by construction. No buffer_inv.

#define NCLS 340
#define NCLS4 85
#define UNROLL 8

__device__ unsigned g_count = 0u;   // zeroed at module load; self-resetting

__global__ void __launch_bounds__(256) lsep_fused(
        const float* __restrict__ in,
        const int* __restrict__ tgt,
        double* __restrict__ partial,
        float* __restrict__ out,
        int B, int nblocks) {
    const int tid = blockIdx.x * blockDim.x + threadIdx.x;
    const int T = gridDim.x * blockDim.x;     // total threads = n4/8
    const float4* __restrict__ in4 = (const float4*)in;

    int   idx[UNROLL], row[UNROLL], t[UNROLL];
    float4 v[UNROLL];
    float pos[UNROLL];

    // epoch 1: issue all v-loads and tgt-loads (independent)
    #pragma unroll
    for (int u = 0; u < UNROLL; ++u) {
        idx[u] = tid + u * T;
        row[u] = idx[u] / NCLS4;              // magic-mul
        v[u]   = in4[idx[u]];
    }
    #pragma unroll
    for (int u = 0; u < UNROLL; ++u)
        t[u] = tgt[row[u]];

    // epoch 2: dependent pos gathers (L1/L2-warm: 85 consecutive tids share
    // a row, so these are near-broadcast)
    #pragma unroll
    for (int u = 0; u < UNROLL; ++u)
        pos[u] = in[row[u] * NCLS + t[u]];

    float s = 0.0f;
    #pragma unroll
    for (int u = 0; u < UNROLL; ++u) {
        float e = __expf(v[u].x) + __expf(v[u].y) +
                  __expf(v[u].z) + __expf(v[u].w);
        s += e * __expf(-pos[u]);
    }

    // wave reduce (64 lanes)
    #pragma unroll
    for (int off = 32; off > 0; off >>= 1)
        s += __shfl_down(s, off, 64);

    __shared__ float wsum[4];
    __shared__ int   isLast;
    const int lane = threadIdx.x & 63;
    const int wave = threadIdx.x >> 6;
    if (lane == 0) wsum[wave] = s;
    __syncthreads();

    if (threadIdx.x == 0) {
        double bs = (double)(wsum[0] + wsum[1] + wsum[2] + wsum[3]);
        // sc1 write-through store: lands at the device coherent point.
        __hip_atomic_store(&partial[blockIdx.x], bs,
                           __ATOMIC_RELAXED, __HIP_MEMORY_SCOPE_AGENT);
        // Wait for the store's coherent-point ACK. This is the entire
        // release we need (no plain global stores exist to flush -> no
        // buffer_wbl2, no L2 walk).
        asm volatile("s_waitcnt vmcnt(0)" ::: "memory");
        // RELAXED counter RMW: executes at the coherent point; ordered
        // after the partial by the waitcnt above.
        unsigned prev = __hip_atomic_fetch_add(&g_count, 1u,
                           __ATOMIC_RELAXED, __HIP_MEMORY_SCOPE_AGENT);
        isLast = (prev == (unsigned)nblocks - 1u) ? 1 : 0;
    }
    __syncthreads();
    if (isLast == 0) return;

    // last block: every partial is acked at the coherent point (each
    // preceded its block's counter RMW). Relaxed agent (sc1) loads read
    // the coherent point directly — no acquire fence, no buffer_inv.
    double d = 0.0;
    for (int i = threadIdx.x; i < nblocks; i += 256)
        d += __hip_atomic_load(&partial[i], __ATOMIC_RELAXED,
                               __HIP_MEMORY_SCOPE_AGENT);
    #pragma unroll
    for (int off = 32; off > 0; off >>= 1)
        d += __shfl_down(d, off, 64);

    __shared__ double dsum[4];
    if (lane == 0) dsum[wave] = d;
    __syncthreads();
    if (threadIdx.x == 0) {
        double total = dsum[0] + dsum[1] + dsum[2] + dsum[3];
        out[0] = (float)log1p(total - (double)B);  // remove j==y_i terms
        // reset for the next graph replay (stream-ordered, so no race)
        __hip_atomic_store(&g_count, 0u,
                           __ATOMIC_RELAXED, __HIP_MEMORY_SCOPE_AGENT);
    }
}

extern "C" void kernel_launch(void* const* d_in, const int* in_sizes, int n_in,
                              void* d_out, int out_size, void* d_ws, size_t ws_size,
                              hipStream_t stream) {
    const float* in  = (const float*)d_in[0];
    const int*   tgt = (const int*)d_in[1];
    const int B  = in_sizes[1];          // 65536 rows
    const int n4 = in_sizes[0] / 4;      // 5,570,560 float4s

    const int threads = n4 / UNROLL;     // 696,320 (exact)
    const int blocks  = threads / 256;   // 2720 (exact)

    double* partial = (double*)d_ws;     // 2720 * 8B = 21.8 KB scratch

    lsep_fused<<<blocks, 256, 0, stream>>>(in, tgt, partial,
                                           (float*)d_out, B, blocks);
}

// Round 5
// 138.694 us; speedup vs baseline: 2.4440x; 1.0411x over previous
//
#include <hip/hip_runtime.h>
#include <math.h>

// LSEP loss: log1p( sum_i sum_{j!=y_i} exp(x[i,j] - x[i,y_i]) )
//   = log1p( sum_i exp(-pos_i) * sum_j exp(x[i,j])  -  B )
// C = 340 -> every float4 lies within one row, row = idx4/85.
// n4 = 65536*85 = 5,570,560 = 8 * 696,320 -> UNROLL=8, 2720 blocks x 256.
//
// R1: batched loads (2 memory epochs) -> main body ~15us, near 14.2us
//     compulsory-read roofline.
// R2: per-block agent ACQUIRE (buffer_inv sc1, full L2 inv) = 243us.
// R4: per-block agent RELEASE (buffer_wbl2 sc1, L2 walk) = 144us/dispatch.
// R5: sc1 store + bare vmcnt(0) + relaxed RMW = correct, fused ~36us, but
//     total 144.4 > 130.3 two-kernel baseline. Remaining cost is
//     traffic-independent: (a) 2720 same-address RMWs serializing at the
//     coherent point (~5-15ns each, clustered arrivals -> multi-us tail);
//     (b) every loser block holds all 4 waves at __syncthreads while
//     thread 0 waits out store-ack + RMW round trips -> late retirement,
//     late next-generation block start.
// R6 (this version):
//     - 64 distributed slot counters (one per 128B line, slot=blk&63 so
//       temporally-clustered completions hit different slots), two-level:
//       slot-last -> g_final. ~43 parallel RMWs/slot + 64 on g_final.
//     - waves 1-3 exit right after the LDS reduce barrier; only wave 0
//       does the handshake; isLast broadcast by __shfl (no 2nd barrier).
//     - winner = wave 0 only: 43 independent sc1 loads/lane + shfl
//       reduce; lane l resets g_slot[l], lane 0 resets g_final.
//     Ordering unchanged from proven R5: sc1 write-through store ->
//     s_waitcnt vmcnt(0) (coherent-point ack) -> RMW; RMW-to-RMW ordered
//     by returned-value dependency. No wbl2, no buffer_inv anywhere.

#define NCLS 340
#define NCLS4 85
#define UNROLL 8
#define NSLOT 64

__device__ unsigned g_slot[NSLOT * 32];  // one counter per 128B line; load-zeroed
__device__ unsigned g_final = 0u;        // load-zeroed; winner self-resets all

__global__ void __launch_bounds__(256) lsep_fused(
        const float* __restrict__ in,
        const int* __restrict__ tgt,
        double* __restrict__ partial,
        float* __restrict__ out,
        int B, int nblocks) {
    const int tid = blockIdx.x * blockDim.x + threadIdx.x;
    const int T = gridDim.x * blockDim.x;     // total threads = n4/8
    const float4* __restrict__ in4 = (const float4*)in;

    int   idx[UNROLL], row[UNROLL], t[UNROLL];
    float4 v[UNROLL];
    float pos[UNROLL];

    // epoch 1: issue all v-loads and tgt-loads (independent)
    #pragma unroll
    for (int u = 0; u < UNROLL; ++u) {
        idx[u] = tid + u * T;
        row[u] = idx[u] / NCLS4;              // magic-mul
        v[u]   = in4[idx[u]];
    }
    #pragma unroll
    for (int u = 0; u < UNROLL; ++u)
        t[u] = tgt[row[u]];

    // epoch 2: dependent pos gathers (L1/L2-warm: 85 consecutive tids share
    // a row, so these are near-broadcast)
    #pragma unroll
    for (int u = 0; u < UNROLL; ++u)
        pos[u] = in[row[u] * NCLS + t[u]];

    float s = 0.0f;
    #pragma unroll
    for (int u = 0; u < UNROLL; ++u) {
        float e = __expf(v[u].x) + __expf(v[u].y) +
                  __expf(v[u].z) + __expf(v[u].w);
        s += e * __expf(-pos[u]);
    }

    // wave reduce (64 lanes)
    #pragma unroll
    for (int off = 32; off > 0; off >>= 1)
        s += __shfl_down(s, off, 64);

    __shared__ float wsum[4];
    const int lane = threadIdx.x & 63;
    const int wave = threadIdx.x >> 6;
    if (lane == 0) wsum[wave] = s;
    __syncthreads();

    // waves 1-3 are done: retire their wave slots immediately.
    if (wave != 0) return;

    // ---- wave 0 only from here ----
    int last = 0;
    if (lane == 0) {
        double bs = (double)(wsum[0] + wsum[1] + wsum[2] + wsum[3]);
        // sc1 write-through store: lands at the device coherent point.
        __hip_atomic_store(&partial[blockIdx.x], bs,
                           __ATOMIC_RELAXED, __HIP_MEMORY_SCOPE_AGENT);
        // wait for the coherent-point ACK — the only ordering needed
        // (no plain global stores exist -> no wbl2 required).
        asm volatile("s_waitcnt vmcnt(0)" ::: "memory");

        const unsigned slot = (unsigned)blockIdx.x & (NSLOT - 1);
        const unsigned q    = (unsigned)nblocks >> 6;       // 42
        const unsigned rem  = (unsigned)nblocks & (NSLOT-1);// 32
        const unsigned quota = slot < rem ? q + 1 : q;      // 43 or 42

        unsigned prev = __hip_atomic_fetch_add(&g_slot[slot * 32], 1u,
                           __ATOMIC_RELAXED, __HIP_MEMORY_SCOPE_AGENT);
        if (prev == quota - 1u) {
            // slot RMW's returned value forces completion before this
            // issues -> all this slot's partials are acked.
            unsigned fprev = __hip_atomic_fetch_add(&g_final, 1u,
                               __ATOMIC_RELAXED, __HIP_MEMORY_SCOPE_AGENT);
            last = (fprev == NSLOT - 1u) ? 1 : 0;
        }
    }
    last = __shfl(last, 0, 64);
    if (!last) return;

    // ---- winner wave: all partials are acked at the coherent point ----
    double d = 0.0;
    for (int i = lane; i < nblocks; i += 64)   // 43 independent sc1 loads
        d += __hip_atomic_load(&partial[i], __ATOMIC_RELAXED,
                               __HIP_MEMORY_SCOPE_AGENT);
    #pragma unroll
    for (int off = 32; off > 0; off >>= 1)
        d += __shfl_down(d, off, 64);

    // reset counters for the next graph replay (kernel-end release makes
    // these visible before any subsequent dispatch).
    __hip_atomic_store(&g_slot[lane * 32], 0u,
                       __ATOMIC_RELAXED, __HIP_MEMORY_SCOPE_AGENT);
    if (lane == 0) {
        __hip_atomic_store(&g_final, 0u,
                           __ATOMIC_RELAXED, __HIP_MEMORY_SCOPE_AGENT);
        out[0] = (float)log1p(d - (double)B);  // remove j==y_i terms
    }
}

extern "C" void kernel_launch(void* const* d_in, const int* in_sizes, int n_in,
                              void* d_out, int out_size, void* d_ws, size_t ws_size,
                              hipStream_t stream) {
    const float* in  = (const float*)d_in[0];
    const int*   tgt = (const int*)d_in[1];
    const int B  = in_sizes[1];          // 65536 rows
    const int n4 = in_sizes[0] / 4;      // 5,570,560 float4s

    const int threads = n4 / UNROLL;     // 696,320 (exact)
    const int blocks  = threads / 256;   // 2720 (exact)

    double* partial = (double*)d_ws;     // 2720 * 8B = 21.8 KB scratch

    lsep_fused<<<blocks, 256, 0, stream>>>(in, tgt, partial,
                                           (float*)d_out, B, blocks);
}

// Round 6
// 128.731 us; speedup vs baseline: 2.6331x; 1.0774x over previous
//
#include <hip/hip_runtime.h>
#include <math.h>

// LSEP loss: log1p( sum_i sum_{j!=y_i} exp(x[i,j] - x[i,y_i]) )
//   = log1p( sum_i exp(-pos_i) * sum_j exp(x[i,j])  -  B )
// C = 340 -> every float4 lies within one row, row = idx4/85.
// n4 = 65536*85 = 5,570,560 = 8 * 696,320 -> UNROLL=8, 2720 blocks x 256.
//
// R1: batched loads (2 epochs) -> main body ~15us (14.2us compulsory-read).
// R2: per-block agent ACQUIRE (buffer_inv sc1) = 243us. Never again.
// R4: per-block agent RELEASE (buffer_wbl2 sc1 L2 walk) = 144us/dispatch.
// R5: sc1 store + bare vmcnt(0) + relaxed RMW correct; same-address
//     g_count RMW x2720 serialized at the coherent point (~14us tail).
// R6: 64 slot counters fixed the RMW tail BUT the winner loop (43
//     dependency-chained sc1 loads/lane; compilers don't pipeline across
//     atomics ~ 43 x 250ns = 10.7us serial) kept fused at ~28us.
//     Ledger: 15.5 body + 10.7 winner + ~1.5 handshake = 28 (closes).
// R7 (this version): make the reduce tree match the machine.
//   - 64 fp64 atomic-add slot accumulators (one per 128B line): each WAVE
//     adds its wave-sum into g_ssum[slot]. Winner reads exactly 64 values
//     (one sc1 load per lane, ~0.5us). partial[] eliminated.
//   - barrier-free + LDS-free: all 4 waves publish independently
//     (quota = 4 x blocks-per-slot); no __syncthreads, no LDS, per-wave
//     retirement. Winner is the globally-last wave.
//   - ordering = proven R5/R6 chain: sc1 RMW -> s_waitcnt vmcnt(0) (ack)
//     -> count RMW (returned value => complete) -> g_final (64 arrivals
//     only). No wbl2, no buffer_inv anywhere.
//   - winner MUST use sc1 loads: its own XCD L2 holds stale g_ssum lines
//     from the PREVIOUS replay's winner read (no cross-XCD invalidation).

#define NCLS 340
#define NCLS4 85
#define UNROLL 8
#define NSLOT 64

__device__ double   g_ssum[NSLOT * 16];  // 1 fp64 accumulator / 128B line; load-zeroed
__device__ unsigned g_scnt[NSLOT * 32];  // 1 counter / 128B line; load-zeroed
__device__ unsigned g_final = 0u;        // touched by 64 slot-winners only

__global__ void __launch_bounds__(256) lsep_fused(
        const float* __restrict__ in,
        const int* __restrict__ tgt,
        float* __restrict__ out,
        int B, int nblocks) {
    const int tid = blockIdx.x * blockDim.x + threadIdx.x;
    const int T = gridDim.x * blockDim.x;     // total threads = n4/8
    const float4* __restrict__ in4 = (const float4*)in;

    int   idx[UNROLL], row[UNROLL], t[UNROLL];
    float4 v[UNROLL];
    float pos[UNROLL];

    // epoch 1: issue all v-loads and tgt-loads (independent)
    #pragma unroll
    for (int u = 0; u < UNROLL; ++u) {
        idx[u] = tid + u * T;
        row[u] = idx[u] / NCLS4;              // magic-mul
        v[u]   = in4[idx[u]];
    }
    #pragma unroll
    for (int u = 0; u < UNROLL; ++u)
        t[u] = tgt[row[u]];

    // epoch 2: dependent pos gathers (L1/L2-warm: 85 consecutive tids share
    // a row, so these are near-broadcast)
    #pragma unroll
    for (int u = 0; u < UNROLL; ++u)
        pos[u] = in[row[u] * NCLS + t[u]];

    float s = 0.0f;
    #pragma unroll
    for (int u = 0; u < UNROLL; ++u) {
        float e = __expf(v[u].x) + __expf(v[u].y) +
                  __expf(v[u].z) + __expf(v[u].w);
        s += e * __expf(-pos[u]);
    }

    // wave reduce (64 lanes) — the only intra-kernel reduction we need
    #pragma unroll
    for (int off = 32; off > 0; off >>= 1)
        s += __shfl_down(s, off, 64);

    const int lane = threadIdx.x & 63;
    int last = 0;
    if (lane == 0) {
        const unsigned slot  = (unsigned)blockIdx.x & (NSLOT - 1);
        const unsigned qb    = (unsigned)nblocks >> 6;        // 42
        const unsigned rem   = (unsigned)nblocks & (NSLOT-1); // 32
        const unsigned quota = 4u * (slot < rem ? qb + 1u : qb); // waves/slot

        // fp64 atomic add at the coherent point (no return -> fire);
        __hip_atomic_fetch_add(&g_ssum[slot * 16], (double)s,
                               __ATOMIC_RELAXED, __HIP_MEMORY_SCOPE_AGENT);
        // wait for its ACK — the entire ordering we need (no plain global
        // stores exist -> no wbl2; no acquire anywhere -> no buffer_inv).
        asm volatile("s_waitcnt vmcnt(0)" ::: "memory");
        // slot counter: returned value => RMW complete at coherent point,
        // strictly after this wave's fp64 add.
        unsigned prev = __hip_atomic_fetch_add(&g_scnt[slot * 32], 1u,
                               __ATOMIC_RELAXED, __HIP_MEMORY_SCOPE_AGENT);
        if (prev == quota - 1u) {
            unsigned f = __hip_atomic_fetch_add(&g_final, 1u,
                               __ATOMIC_RELAXED, __HIP_MEMORY_SCOPE_AGENT);
            last = (f == NSLOT - 1u) ? 1 : 0;
        }
    }
    last = __shfl(last, 0, 64);
    if (!last) return;

    // ---- globally-last wave: all 64 slot sums are final & acked ----
    double d = __hip_atomic_load(&g_ssum[lane * 16], __ATOMIC_RELAXED,
                                 __HIP_MEMORY_SCOPE_AGENT);
    #pragma unroll
    for (int off = 32; off > 0; off >>= 1)
        d += __shfl_down(d, off, 64);

    // reset for the next graph replay (nothing else is in flight: g_final
    // ==64 proves every wave's RMWs completed). End-of-kernel release
    // publishes these before any subsequent dispatch.
    __hip_atomic_store(&g_ssum[lane * 16], 0.0,
                       __ATOMIC_RELAXED, __HIP_MEMORY_SCOPE_AGENT);
    __hip_atomic_store(&g_scnt[lane * 32], 0u,
                       __ATOMIC_RELAXED, __HIP_MEMORY_SCOPE_AGENT);
    if (lane == 0) {
        __hip_atomic_store(&g_final, 0u,
                           __ATOMIC_RELAXED, __HIP_MEMORY_SCOPE_AGENT);
        out[0] = (float)log1p(d - (double)B);  // remove j==y_i terms
    }
}

extern "C" void kernel_launch(void* const* d_in, const int* in_sizes, int n_in,
                              void* d_out, int out_size, void* d_ws, size_t ws_size,
                              hipStream_t stream) {
    const float* in  = (const float*)d_in[0];
    const int*   tgt = (const int*)d_in[1];
    const int B  = in_sizes[1];          // 65536 rows
    const int n4 = in_sizes[0] / 4;      // 5,570,560 float4s

    const int threads = n4 / UNROLL;     // 696,320 (exact)
    const int blocks  = threads / 256;   // 2720 (exact)

    lsep_fused<<<blocks, 256, 0, stream>>>(in, tgt, (float*)d_out, B, blocks);
}